// Round 1
// baseline (212.137 us; speedup 1.0000x reference)
//
#include <hip/hip_runtime.h>

typedef unsigned short u16;
typedef __attribute__((ext_vector_type(8))) short bf16x8;
typedef __attribute__((ext_vector_type(4))) float f32x4;

#define BK 64

__device__ __forceinline__ u16 f2bf(float f) {
    unsigned u = __float_as_uint(f);
    unsigned r = u + 0x7fffu + ((u >> 16) & 1u);
    return (u16)(r >> 16);
}
__device__ __forceinline__ float bf2f(u16 h) {
    return __uint_as_float(((unsigned)h) << 16);
}

__device__ __forceinline__ void gload_lds16(const u16* g, u16* l) {
    __builtin_amdgcn_global_load_lds(
        (__attribute__((address_space(1))) unsigned int*)(u16*)g,
        (__attribute__((address_space(3))) unsigned int*)l,
        16, 0, 0);
}

// ---------- fused input conversion + rowsum zeroing ----------
// blocks [0,6144): x fp32 -> bf16 (float4/thread)
// blocks [6144,7872): kernel[3][768][768] fp32 -> Wt[j*768+o][d] bf16 (transpose)
// block 7872: zero rowsum[8192]
__global__ __launch_bounds__(256) void cvt_in_kernel(const float* __restrict__ x,
                                                     const float* __restrict__ W,
                                                     u16* __restrict__ xb,
                                                     u16* __restrict__ Wt,
                                                     float* __restrict__ rsum) {
    const int bid = blockIdx.x;
    const int tid = threadIdx.x;
    if (bid < 6144) {
        int i = bid * 256 + tid;
        float4 f = ((const float4*)x)[i];
        ushort4 u;
        u.x = f2bf(f.x); u.y = f2bf(f.y); u.z = f2bf(f.z); u.w = f2bf(f.w);
        ((ushort4*)xb)[i] = u;
    } else if (bid < 7872) {
        __shared__ float t[32][33];
        const int b = bid - 6144;
        const int j = b / 576;
        const int rem = b - j * 576;
        const int d0 = (rem % 24) * 32, o0 = (rem / 24) * 32;
        const int tx = tid & 31, ty = tid >> 5;
#pragma unroll
        for (int i = 0; i < 4; i++) {
            int d = d0 + ty + i * 8;
            t[ty + i * 8][tx] = W[((long)j * 768 + d) * 768 + o0 + tx];
        }
        __syncthreads();
#pragma unroll
        for (int i = 0; i < 4; i++) {
            int o = o0 + ty + i * 8;
            Wt[((long)j * 768 + o) * 768 + d0 + tx] = f2bf(t[tx][ty + i * 8]);
        }
    } else {
        const float4 z4 = {0.f, 0.f, 0.f, 0.f};
#pragma unroll
        for (int j = 0; j < 8; j++) ((float4*)rsum)[tid * 8 + j] = z4;
    }
}

// ---------- GEMM: C = A(MxK) * Bt(NxK)^T, bf16 in, fp32 acc ----------
// BM = TM*32, BN = 128. 4 waves in 2x2; each wave computes (TM*16)x64.
// TM=4 => m97 geometry: 128x128 block tile, 64x64 per wave, 32 MFMA : 16 ds_read
// per BK step (vs 16:12 at TM=2) -- proven ~900 TF class on gfx950.
// MODE 0: QKV. y<12 -> Q/K bf16 direct; y>=12 -> V written TRANSPOSED (Vt) via LDS.
// MODE 1: P~ = exp(s*scale) bf16 + per-row atomic sum into rsum.
// MODE 2: out = acc / rsum[row] -> fp32.
template <int MODE, int TM>
__global__ __launch_bounds__(256)
void gemm_bt_kernel(const u16* __restrict__ A, const u16* __restrict__ Bt,
                    u16* __restrict__ o16, float* __restrict__ o32,
                    u16* __restrict__ vt, float* __restrict__ rsum,
                    int K, long sA, long sB, long sO, int ldc, float scale) {
    constexpr int BM = TM * 32;
    constexpr int TS = BM + (BM == 128 ? 4 : 8);     // V-transpose LDS stride (u16)
    constexpr int SMEM_MAIN = BM * BK + 128 * BK;
    constexpr int SMEM_SZ =
        (MODE == 0 && 128 * TS > SMEM_MAIN) ? 128 * TS : SMEM_MAIN;
    __shared__ u16 smem[SMEM_SZ];
    u16* As = smem;
    u16* Bs = smem + BM * BK;

    const int tid = threadIdx.x;
    const int lane = tid & 63;
    const int wave = tid >> 6;
    const int z = blockIdx.z;

    const u16* Ab = A + (long)z * sA + (long)blockIdx.x * BM * K;
    const u16* Bb = Bt + (long)z * sB + (long)blockIdx.y * 128 * K;

    const int rl = lane >> 3;   // row within 8-row staging group
    const int pc = lane & 7;    // 16B chunk position within row
    const int q = lane >> 4;    // quad
    const int rA = lane & 15;
    const int wm = (wave >> 1) * (TM * 16);
    const int wn = (wave & 1) * 64;

    f32x4 acc[TM][4];
    const f32x4 zero = {0.f, 0.f, 0.f, 0.f};
#pragma unroll
    for (int i = 0; i < TM; i++)
#pragma unroll
        for (int j = 0; j < 4; j++) acc[i][j] = zero;

    for (int k0 = 0; k0 < K; k0 += BK) {
        // XOR swizzle: LDS row r position p holds global chunk p^(r&7)
#pragma unroll
        for (int t = 0; t < TM; ++t) {
            const int issue = wave + t * 4;      // wave-uniform
            const int row = issue * 8 + rl;
            const int gc = pc ^ (row & 7);
            gload_lds16(Ab + (long)row * K + k0 + gc * 8, &As[issue * 512]);
        }
#pragma unroll
        for (int t = 0; t < 4; ++t) {
            const int issue = wave + t * 4;
            const int row = issue * 8 + rl;
            const int gc = pc ^ (row & 7);
            gload_lds16(Bb + (long)row * K + k0 + gc * 8, &Bs[issue * 512]);
        }
        __syncthreads();
#pragma unroll
        for (int kk = 0; kk < BK; kk += 32) {
            const int gchunk = (kk >> 3) + q;
            bf16x8 af[TM], bfr[4];
#pragma unroll
            for (int mi = 0; mi < TM; ++mi) {
                const int R = wm + mi * 16 + rA;
                af[mi] = *(const bf16x8*)&As[R * 64 + ((gchunk ^ (R & 7)) << 3)];
            }
#pragma unroll
            for (int ni = 0; ni < 4; ++ni) {
                const int R = wn + ni * 16 + rA;
                bfr[ni] = *(const bf16x8*)&Bs[R * 64 + ((gchunk ^ (R & 7)) << 3)];
            }
#pragma unroll
            for (int mi = 0; mi < TM; ++mi)
#pragma unroll
                for (int ni = 0; ni < 4; ++ni)
                    acc[mi][ni] = __builtin_amdgcn_mfma_f32_16x16x32_bf16(
                        af[mi], bfr[ni], acc[mi][ni], 0, 0, 0);
        }
        __syncthreads();
    }

    // epilogue: C/D layout col=lane&15, row=quad*4+reg
    const int rowb = blockIdx.x * BM + wm + q * 4;
    const int colb = blockIdx.y * 128 + wn + rA;

    if (MODE == 0 && blockIdx.y >= 12) {
        // V segment -> write transposed (Vt[b][o][s]) via LDS tile [128 o][BM s]
        u16* T = smem;
#pragma unroll
        for (int mi = 0; mi < TM; ++mi)
#pragma unroll
            for (int ni = 0; ni < 4; ++ni) {
                const int lc = wn + ni * 16 + rA;
#pragma unroll
                for (int r = 0; r < 4; ++r) {
                    const int lr = wm + mi * 16 + q * 4 + r;
                    T[lc * TS + lr] = f2bf(acc[mi][ni][r]);
                }
            }
        __syncthreads();
        constexpr int BPB = 2048 / BM;               // blocks per batch in x
        const int b = blockIdx.x / BPB;
        const int s0 = (blockIdx.x % BPB) * BM;
        const int o0 = (blockIdx.y - 12) * 128;
        const int ol = tid >> 1, h = (tid & 1) * (BM / 2);
        u16* dst = vt + ((long)b * 768 + o0 + ol) * 2048 + s0 + h;
        const u16* src = &T[ol * TS + h];
#pragma unroll
        for (int j = 0; j < BM / 16; ++j)
            *(uint4*)(dst + j * 8) = *(const uint4*)(src + j * 8);
        return;
    }

#pragma unroll
    for (int mi = 0; mi < TM; ++mi) {
        if (MODE == 0) {
            const int seg = blockIdx.y / 6;           // 0=Q, 1=K (block-uniform)
            const int ocol = colb - seg * 768;
#pragma unroll
            for (int ni = 0; ni < 4; ++ni)
#pragma unroll
                for (int r = 0; r < 4; ++r)
                    o16[(long)seg * 6291456 + (long)(rowb + mi * 16 + r) * 768 +
                        ocol + ni * 16] = f2bf(acc[mi][ni][r]);
        } else if (MODE == 1) {
            u16* dst = o16 + (long)z * sO;
            float rs[4] = {0.f, 0.f, 0.f, 0.f};
#pragma unroll
            for (int ni = 0; ni < 4; ++ni)
#pragma unroll
                for (int r = 0; r < 4; ++r) {
                    const float p = __expf(acc[mi][ni][r] * scale);
                    const u16 pb = f2bf(p);
                    dst[(long)(rowb + mi * 16 + r) * ldc + colb + ni * 16] = pb;
                    rs[r] += bf2f(pb);
                }
#pragma unroll
            for (int r = 0; r < 4; ++r) {
#pragma unroll
                for (int off = 1; off <= 8; off <<= 1) rs[r] += __shfl_xor(rs[r], off);
                if (rA == 0)
                    atomicAdd(&rsum[z * 2048 + rowb + mi * 16 + r], rs[r]);
            }
        } else {
            float* dst = o32 + (long)z * sO;
            const float4 rs4 = *(const float4*)&rsum[z * 2048 + rowb + mi * 16];
            const float inv[4] = {1.f / rs4.x, 1.f / rs4.y, 1.f / rs4.z, 1.f / rs4.w};
#pragma unroll
            for (int ni = 0; ni < 4; ++ni)
#pragma unroll
                for (int r = 0; r < 4; ++r)
                    dst[(long)(rowb + mi * 16 + r) * ldc + colb + ni * 16] =
                        acc[mi][ni][r] * inv[r];
        }
    }
}

extern "C" void kernel_launch(void* const* d_in, const int* in_sizes, int n_in,
                              void* d_out, int out_size, void* d_ws, size_t ws_size,
                              hipStream_t stream) {
    const float* x = (const float*)d_in[0];     // [4,2048,768]
    const float* w = (const float*)d_in[1];     // [3,768,768]
    float* out = (float*)d_out;                 // [4,2048,768]

    const long NX = 6291456L;   // 4*2048*768
    const long NS = 16777216L;  // 4*2048*2048

    // layout: [Sb: NS][Qb: NX][Kb: NX][Vt: NX][rowsum: 8192 f32]  (~71.3 MB)
    // xb+wt overlay the Sb region (dead before GEMM2 writes Sb)
    u16* Sb = (u16*)d_ws;
    u16* xb = Sb;                 // NX
    u16* wt = Sb + NX;            // 1769472  (< NS)
    u16* Qb = Sb + NS;
    u16* Kb = Qb + NX;
    u16* Vt = Kb + NX;
    float* rowsum = (float*)(Vt + NX);

    // 1. x -> bf16; W -> Wt[2304][768] bf16 transposed; rowsum <- 0
    cvt_in_kernel<<<7873, 256, 0, stream>>>(x, w, xb, wt, rowsum);
    // 2. QKV: [8192,768] x [2304,768]^T; Q,K direct; V transposed into Vt
    gemm_bt_kernel<0, 4><<<dim3(64, 18, 1), 256, 0, stream>>>(
        xb, wt, Qb, nullptr, Vt, nullptr, 768, 0L, 0L, 0L, 768, 1.0f);
    // 3. P~ = exp(QK^T/sqrt(300)) bf16 -> Sb, + rowsum atomics
    gemm_bt_kernel<1, 4><<<dim3(16, 16, 4), 256, 0, stream>>>(
        Qb, Kb, Sb, nullptr, nullptr, rowsum, 768, 2048L * 768, 2048L * 768,
        2048L * 2048, 2048, 0.057735026918962574f);
    // 4. out = (P~ x Vt^T) / rowsum -> fp32
    gemm_bt_kernel<2, 4><<<dim3(16, 6, 4), 256, 0, stream>>>(
        Sb, Vt, nullptr, out, nullptr, rowsum, 2048, 2048L * 2048, 768L * 2048,
        2048L * 768, 768, 1.0f);
}

// Round 3
// 194.762 us; speedup vs baseline: 1.0892x; 1.0892x over previous
//
#include <hip/hip_runtime.h>

typedef unsigned short u16;
typedef __attribute__((ext_vector_type(8))) short bf16x8;
typedef __attribute__((ext_vector_type(4))) float f32x4;

#define BK 64
#define TM 2
#define BM 64

__device__ __forceinline__ u16 f2bf(float f) {
    unsigned u = __float_as_uint(f);
    unsigned r = u + 0x7fffu + ((u >> 16) & 1u);
    return (u16)(r >> 16);
}
__device__ __forceinline__ float bf2f(u16 h) {
    return __uint_as_float(((unsigned)h) << 16);
}

__device__ __forceinline__ void gload_lds16(const u16* g, u16* l) {
    __builtin_amdgcn_global_load_lds(
        (__attribute__((address_space(1))) unsigned int*)(u16*)g,
        (__attribute__((address_space(3))) unsigned int*)l,
        16, 0, 0);
}

// ---------- fused input conversion + rowsum zeroing ----------
__global__ __launch_bounds__(256) void cvt_in_kernel(const float* __restrict__ x,
                                                     const float* __restrict__ W,
                                                     u16* __restrict__ xb,
                                                     u16* __restrict__ Wt,
                                                     float* __restrict__ rsum) {
    const int bid = blockIdx.x;
    const int tid = threadIdx.x;
    if (bid < 6144) {
        int i = bid * 256 + tid;
        float4 f = ((const float4*)x)[i];
        ushort4 u;
        u.x = f2bf(f.x); u.y = f2bf(f.y); u.z = f2bf(f.z); u.w = f2bf(f.w);
        ((ushort4*)xb)[i] = u;
    } else if (bid < 7872) {
        __shared__ float t[32][33];
        const int b = bid - 6144;
        const int j = b / 576;
        const int rem = b - j * 576;
        const int d0 = (rem % 24) * 32, o0 = (rem / 24) * 32;
        const int tx = tid & 31, ty = tid >> 5;
#pragma unroll
        for (int i = 0; i < 4; i++) {
            int d = d0 + ty + i * 8;
            t[ty + i * 8][tx] = W[((long)j * 768 + d) * 768 + o0 + tx];
        }
        __syncthreads();
#pragma unroll
        for (int i = 0; i < 4; i++) {
            int o = o0 + ty + i * 8;
            Wt[((long)j * 768 + o) * 768 + d0 + tx] = f2bf(t[tx][ty + i * 8]);
        }
    } else {
        const float4 z4 = {0.f, 0.f, 0.f, 0.f};
#pragma unroll
        for (int j = 0; j < 8; j++) ((float4*)rsum)[tid * 8 + j] = z4;
    }
}

// stage one (A,B) K-tile into an LDS buffer via global_load_lds (XOR-swizzled)
__device__ __forceinline__ void stage_tiles(const u16* Ab, const u16* Bb, int K,
                                            int k0, u16* As, u16* Bs, int wave,
                                            int rl, int pc) {
#pragma unroll
    for (int t = 0; t < TM; ++t) {
        const int issue = wave + t * 4;      // wave-uniform
        const int row = issue * 8 + rl;
        const int gc = pc ^ (row & 7);
        gload_lds16(Ab + (long)row * K + k0 + gc * 8, &As[issue * 512]);
    }
#pragma unroll
    for (int t = 0; t < 4; ++t) {
        const int issue = wave + t * 4;
        const int row = issue * 8 + rl;
        const int gc = pc ^ (row & 7);
        gload_lds16(Bb + (long)row * K + k0 + gc * 8, &Bs[issue * 512]);
    }
}

// 16 MFMA on one staged K-tile
__device__ __forceinline__ void compute_tile(const u16* As, const u16* Bs,
                                             f32x4 (&acc)[TM][4], int wm, int wn,
                                             int q, int rA) {
#pragma unroll
    for (int kk = 0; kk < BK; kk += 32) {
        const int gchunk = (kk >> 3) + q;
        bf16x8 af[TM], bfr[4];
#pragma unroll
        for (int mi = 0; mi < TM; ++mi) {
            const int R = wm + mi * 16 + rA;
            af[mi] = *(const bf16x8*)&As[R * 64 + ((gchunk ^ (R & 7)) << 3)];
        }
#pragma unroll
        for (int ni = 0; ni < 4; ++ni) {
            const int R = wn + ni * 16 + rA;
            bfr[ni] = *(const bf16x8*)&Bs[R * 64 + ((gchunk ^ (R & 7)) << 3)];
        }
#pragma unroll
        for (int mi = 0; mi < TM; ++mi)
#pragma unroll
            for (int ni = 0; ni < 4; ++ni)
                acc[mi][ni] = __builtin_amdgcn_mfma_f32_16x16x32_bf16(
                    af[mi], bfr[ni], acc[mi][ni], 0, 0, 0);
    }
}

// ---------- GEMM: C = A(MxK) * Bt(NxK)^T, bf16 in, fp32 acc ----------
// 64x128 tile, double-buffered LDS (T3-minimum 2-phase: prefetch next K-tile
// before computing current; ONE __syncthreads per K-step), XCD-chunked swizzle.
// MODE 0: QKV. by<12 -> Q/K bf16 direct; by>=12 -> V written TRANSPOSED via LDS.
// MODE 1: P~ = exp(s*scale) bf16 + per-row atomic sum into rsum.
// MODE 2: out = acc / rsum[row] -> fp32.
template <int MODE>
__global__ __launch_bounds__(256)
void gemm_bt_kernel(const u16* __restrict__ A, const u16* __restrict__ Bt,
                    u16* __restrict__ o16, float* __restrict__ o32,
                    u16* __restrict__ vt, float* __restrict__ rsum,
                    int K, long sA, long sB, long sO, int ldc, float scale,
                    int ny, int nxy) {
    __shared__ __align__(16) u16 smem[2 * (BM * BK + 128 * BK)];  // 49152 B
    u16* A0 = smem;
    u16* B0 = smem + BM * BK;
    u16* A1 = smem + (BM * BK + 128 * BK);
    u16* B1 = A1 + BM * BK;

    // bijective XCD-chunked swizzle: each XCD gets a contiguous task range,
    // ordered by-inner so the B z-slice (~3-3.5MB) stays L2-resident per XCD
    // and each A panel is reused by consecutive blocks.
    const int nb = gridDim.x;            // divisible by 8
    const int chunk = nb >> 3;
    const int nl = (blockIdx.x & 7) * chunk + (blockIdx.x >> 3);
    const int bz = nl / nxy;
    const int rem = nl - bz * nxy;
    const int bx = rem / ny;
    const int by = rem - bx * ny;

    const int tid = threadIdx.x;
    const int lane = tid & 63;
    const int wave = tid >> 6;

    const u16* Ab = A + (long)bz * sA + (long)bx * BM * K;
    const u16* Bb = Bt + (long)bz * sB + (long)by * 128 * K;

    const int rl = lane >> 3;   // row within 8-row staging group
    const int pc = lane & 7;    // 16B chunk position within row
    const int q = lane >> 4;    // quad
    const int rA = lane & 15;
    const int wm = (wave >> 1) * (TM * 16);
    const int wn = (wave & 1) * 64;

    f32x4 acc[TM][4];
    const f32x4 zero = {0.f, 0.f, 0.f, 0.f};
#pragma unroll
    for (int i = 0; i < TM; i++)
#pragma unroll
        for (int j = 0; j < 4; j++) acc[i][j] = zero;

    // prologue: stage tile 0 into buf0
    stage_tiles(Ab, Bb, K, 0, A0, B0, wave, rl, pc);
    __syncthreads();

    // main loop, 2 K-steps per iteration (K/BK is even: 12 or 32)
    for (int k0 = 0; k0 < K; k0 += 2 * BK) {
        if (k0 + BK < K)
            stage_tiles(Ab, Bb, K, k0 + BK, A1, B1, wave, rl, pc);
        compute_tile(A0, B0, acc, wm, wn, q, rA);
        __syncthreads();   // drains buf1 staging; all done reading buf0
        if (k0 + 2 * BK < K)
            stage_tiles(Ab, Bb, K, k0 + 2 * BK, A0, B0, wave, rl, pc);
        compute_tile(A1, B1, acc, wm, wn, q, rA);
        __syncthreads();
    }

    // epilogue: C/D layout col=lane&15, row=quad*4+reg
    const int rowb = bx * BM + wm + q * 4;
    const int colb = by * 128 + wn + rA;

    if (MODE == 0 && by >= 12) {
        // V segment -> write transposed (Vt[b][o][s]) via LDS tile [128 o][72 pad]
        u16* T = smem;
#pragma unroll
        for (int mi = 0; mi < TM; ++mi)
#pragma unroll
            for (int ni = 0; ni < 4; ++ni) {
                const int lc = wn + ni * 16 + rA;
#pragma unroll
                for (int r = 0; r < 4; ++r) {
                    const int lr = wm + mi * 16 + q * 4 + r;
                    T[lc * 72 + lr] = f2bf(acc[mi][ni][r]);
                }
            }
        __syncthreads();
        const int b = bx >> 5;
        const int s0 = (bx & 31) * 64;
        const int o0 = (by - 12) * 128;
        const int ol = tid >> 1, h = (tid & 1) * 32;
        u16* dst = vt + ((long)b * 768 + o0 + ol) * 2048 + s0 + h;
        const u16* src = &T[ol * 72 + h];
#pragma unroll
        for (int j = 0; j < 4; ++j)
            *(uint4*)(dst + j * 8) = *(const uint4*)(src + j * 8);
        return;
    }

#pragma unroll
    for (int mi = 0; mi < TM; ++mi) {
        if (MODE == 0) {
            const int seg = by / 6;           // 0=Q, 1=K (block-uniform)
            const int ocol = colb - seg * 768;
#pragma unroll
            for (int ni = 0; ni < 4; ++ni)
#pragma unroll
                for (int r = 0; r < 4; ++r)
                    o16[(long)seg * 6291456 + (long)(rowb + mi * 16 + r) * 768 +
                        ocol + ni * 16] = f2bf(acc[mi][ni][r]);
        } else if (MODE == 1) {
            u16* dst = o16 + (long)bz * sO;
            float rs[4] = {0.f, 0.f, 0.f, 0.f};
#pragma unroll
            for (int ni = 0; ni < 4; ++ni)
#pragma unroll
                for (int r = 0; r < 4; ++r) {
                    const float p = __expf(acc[mi][ni][r] * scale);
                    const u16 pb = f2bf(p);
                    dst[(long)(rowb + mi * 16 + r) * ldc + colb + ni * 16] = pb;
                    rs[r] += bf2f(pb);
                }
#pragma unroll
            for (int r = 0; r < 4; ++r) {
#pragma unroll
                for (int off = 1; off <= 8; off <<= 1) rs[r] += __shfl_xor(rs[r], off);
                if (rA == 0)
                    atomicAdd(&rsum[bz * 2048 + rowb + mi * 16 + r], rs[r]);
            }
        } else {
            float* dst = o32 + (long)bz * sO;
            const float4 rs4 = *(const float4*)&rsum[bz * 2048 + rowb + mi * 16];
            const float inv[4] = {1.f / rs4.x, 1.f / rs4.y, 1.f / rs4.z, 1.f / rs4.w};
#pragma unroll
            for (int ni = 0; ni < 4; ++ni)
#pragma unroll
                for (int r = 0; r < 4; ++r)
                    dst[(long)(rowb + mi * 16 + r) * ldc + colb + ni * 16] =
                        acc[mi][ni][r] * inv[r];
        }
    }
}

extern "C" void kernel_launch(void* const* d_in, const int* in_sizes, int n_in,
                              void* d_out, int out_size, void* d_ws, size_t ws_size,
                              hipStream_t stream) {
    const float* x = (const float*)d_in[0];     // [4,2048,768]
    const float* w = (const float*)d_in[1];     // [3,768,768]
    float* out = (float*)d_out;                 // [4,2048,768]

    const long NX = 6291456L;   // 4*2048*768
    const long NS = 16777216L;  // 4*2048*2048

    // layout: [Sb: NS][Qb: NX][Kb: NX][Vt: NX][rowsum: 8192 f32]  (~71.3 MB)
    // xb+wt overlay the Sb region (dead before GEMM2 writes Sb)
    u16* Sb = (u16*)d_ws;
    u16* xb = Sb;                 // NX
    u16* wt = Sb + NX;            // 1769472  (< NS)
    u16* Qb = Sb + NS;
    u16* Kb = Qb + NX;
    u16* Vt = Kb + NX;
    float* rowsum = (float*)(Vt + NX);

    // 1. x -> bf16; W -> Wt[2304][768] bf16 transposed; rowsum <- 0
    cvt_in_kernel<<<7873, 256, 0, stream>>>(x, w, xb, wt, rowsum);
    // 2. QKV: [8192,768] x [2304,768]^T; Q,K direct; V transposed into Vt
    //    tasks = 128 x 18 = 2304 (x outer, y inner after swizzle)
    gemm_bt_kernel<0><<<2304, 256, 0, stream>>>(
        xb, wt, Qb, nullptr, Vt, nullptr, 768, 0L, 0L, 0L, 768, 1.0f, 18, 2304);
    // 3. P~ = exp(QK^T/sqrt(300)) bf16 -> Sb, + rowsum atomics
    //    tasks = 32 x 16 x 4 = 2048
    gemm_bt_kernel<1><<<2048, 256, 0, stream>>>(
        Qb, Kb, Sb, nullptr, nullptr, rowsum, 768, 2048L * 768, 2048L * 768,
        2048L * 2048, 2048, 0.057735026918962574f, 16, 512);
    // 4. out = (P~ x Vt^T) / rowsum -> fp32;  tasks = 32 x 6 x 4 = 768
    gemm_bt_kernel<2><<<768, 256, 0, stream>>>(
        Sb, Vt, nullptr, out, nullptr, rowsum, 2048, 2048L * 2048, 768L * 2048,
        2048L * 768, 768, 1.0f, 6, 192);
}